// Round 10
// baseline (336.905 us; speedup 1.0000x reference)
//
#include <hip/hip_runtime.h>
#include <cstdint>
#include <cstddef>

#define NEXPERT 32
#define KIN 256
#define NOUT 256
#define NTOK 524288
#define BM 32   // tile rows; LDS = 32KB -> 4 blocks/CU at __launch_bounds__(256,4)

typedef float f32x4 __attribute__((ext_vector_type(4)));
typedef __bf16 bf16x8 __attribute__((ext_vector_type(8)));
typedef unsigned short u16;
typedef u16 u16x8 __attribute__((ext_vector_type(8)));
typedef unsigned int u32;

union BF8 { u16x8 u; bf16x8 b; };

__device__ __forceinline__ u16 f2bf(float f) {
  unsigned u = __float_as_uint(f);
  return (u16)((u + 0x7FFFu + ((u >> 16) & 1u)) >> 16);  // RNE
}

#define GLDS(gp, lp) __builtin_amdgcn_global_load_lds(                      \
    (const __attribute__((address_space(1))) u32*)(gp),                      \
    (__attribute__((address_space(3))) u32*)(u32)(uintptr_t)(lp), 16, 0, 0)

#define VMW(n) asm volatile("s_waitcnt vmcnt(" n ")" ::: "memory")
#define BAR()  do { __builtin_amdgcn_sched_barrier(0);                       \
                    __builtin_amdgcn_s_barrier();                            \
                    __builtin_amdgcn_sched_barrier(0); } while (0)

// ---- prologue: pack W fp32 -> bf16 in MFMA-fragment order ----
// 16B unit t = ((e*8 + kc)*16 + n16)*64 + lane;
// lane holds W[e][n16*16 + (lane&15)][kc*32 + (lane>>4)*8 + j], j=0..7.
__global__ void pack_w_kernel(const float* __restrict__ w, u16* __restrict__ wb) {
  const int t    = blockIdx.x * 256 + threadIdx.x;   // 0..262143
  const int lane = t & 63;
  const int n16  = (t >> 6) & 15;
  const int kc   = (t >> 10) & 7;
  const int e    = t >> 13;
  const float* src = w + (size_t)e * 65536 + (size_t)(n16 * 16 + (lane & 15)) * 256
                       + kc * 32 + (lane >> 4) * 8;
  const float4 a = *reinterpret_cast<const float4*>(src);
  const float4 b = *reinterpret_cast<const float4*>(src + 4);
  u16x8 h;
  h[0]=f2bf(a.x); h[1]=f2bf(a.y); h[2]=f2bf(a.z); h[3]=f2bf(a.w);
  h[4]=f2bf(b.x); h[5]=f2bf(b.y); h[6]=f2bf(b.z); h[7]=f2bf(b.w);
  *reinterpret_cast<u16x8*>(wb + (size_t)t * 8) = h;
}

// ---- B fragments for one K-step (2 chunks x 4 n), coalesced 1KB loads ----
template<bool WSBF>
__device__ __forceinline__ void loadBstep(const u16* wEL, const float* wF,
                                          int wv, int l15, int lg, int s,
                                          BF8 (&d)[2][4]) {
  if (WSBF) {
#pragma unroll
    for (int c = 0; c < 2; ++c)
#pragma unroll
      for (int n = 0; n < 4; ++n)
        d[c][n].u = *reinterpret_cast<const u16x8*>(
            wEL + (size_t)((2 * s + c) * 16 + (wv << 2) + n) * 512);
  } else {
#pragma unroll
    for (int c = 0; c < 2; ++c)
#pragma unroll
      for (int n = 0; n < 4; ++n) {
        const float4* p = reinterpret_cast<const float4*>(
            wF + (size_t)((wv << 6) + (n << 4) + l15) * KIN + (2 * s + c) * 32 + lg * 8);
        const float4 x = p[0], y = p[1];
        u16x8 h;
        h[0]=f2bf(x.x); h[1]=f2bf(x.y); h[2]=f2bf(x.z); h[3]=f2bf(x.w);
        h[4]=f2bf(y.x); h[5]=f2bf(y.y); h[6]=f2bf(y.z); h[7]=f2bf(y.w);
        d[c][n].u = h;
      }
  }
}

// ---- one K-step of MFMA from staged fp32 LDS buffer (swizzled read) ----
// buf stride 8192 B (32 rows x 256 B); m in {0,1}.
__device__ __forceinline__ void computeStep(const char* sAc, int buf, int l15, int lg,
                                            const BF8 (&bfr)[2][4], f32x4 (&acc)[2][4]) {
  const char* abase = sAc + buf * 8192 + l15 * 256;
#pragma unroll
  for (int c = 0; c < 2; ++c) {
    BF8 af[2];
#pragma unroll
    for (int m = 0; m < 2; ++m) {
      const int g0 = (c << 3) + (lg << 1);
      const f32x4 fa = *reinterpret_cast<const f32x4*>(abase + m * 4096 + (((g0    ) ^ l15) << 4));
      const f32x4 fb = *reinterpret_cast<const f32x4*>(abase + m * 4096 + (((g0 + 1) ^ l15) << 4));
      af[m].b[0]=(__bf16)fa[0]; af[m].b[1]=(__bf16)fa[1];
      af[m].b[2]=(__bf16)fa[2]; af[m].b[3]=(__bf16)fa[3];
      af[m].b[4]=(__bf16)fb[0]; af[m].b[5]=(__bf16)fb[1];
      af[m].b[6]=(__bf16)fb[2]; af[m].b[7]=(__bf16)fb[3];
    }
#pragma unroll
    for (int m = 0; m < 2; ++m)
#pragma unroll
      for (int n = 0; n < 4; ++n)
        acc[m][n] = __builtin_amdgcn_mfma_f32_16x16x32_bf16(
            af[m].b, bfr[c][n].b, acc[m][n], 0, 0, 0);
  }
}

// ---- grouped GEMM: 32x256 tile, 4 waves, 4 K-steps of 64 ----
// R5 schedule scaled down: 4 LDS buffers (8KB each, full A tile), incremental
// stage-ahead, counted vmcnt VMW(12/12/10/0); 4 blocks/CU for 2x TLP.
template<bool WSBF>
__global__ __launch_bounds__(256, 4)
void moe_gemm_kernel(const float* __restrict__ inp,
                     const float* w32,
                     const u16* __restrict__ wpk,
                     const int* __restrict__ counts,
                     float* __restrict__ out)
{
  __shared__ float sA[4 * BM * 64];   // 32 KB

  const int tid  = threadIdx.x;
  const int lane = tid & 63;
  const int wv   = tid >> 6;
  const int l15  = lane & 15;
  const int lg   = lane >> 4;

  // per-wave INCLUSIVE cumsum of counts via shuffle scan (int32/int64 probe)
  const long long* c64 = reinterpret_cast<const long long*>(counts);
  const long long p0 = c64[0];
  const bool is64 = (p0 >= 0 && p0 < (1ll << 31));
  int c = 0;
  if (lane < 32) c = is64 ? (int)c64[lane] : counts[lane];
#pragma unroll
  for (int d = 1; d < 32; d <<= 1) {
    const int o = __shfl_up(c, d, 64);
    if (lane >= d) c += o;
  }
  const int cum = (lane < 32) ? c : 0x7fffffff;

  const int t0 = blockIdx.x * BM;
  const int t1 = t0 + BM;

  // A stage source pointers: instr i covers rows wv*8+i*4..+4;
  // physical 16B unit u'=lane&15 <- logical unit g = u' ^ (row&15).
  const float* gp[2];
#pragma unroll
  for (int i = 0; i < 2; ++i) {
    const int r = (wv << 3) + (i << 2) + (lane >> 4);
    const int g = (lane & 15) ^ (r & 15);
    gp[i] = inp + (size_t)(t0 + r) * KIN + g * 4;
  }
  char* const sAc   = reinterpret_cast<char*>(sA);
  char* const lbase = sAc + wv * 2048;   // + buf*8192 + i*1024 (wave-uniform)

  int rb = t0;
  int e  = __popcll(__ballot(cum <= t0));   // first expert covering t0
  bool first = true;

  while (rb < t1) {
    const int re = min(t1, __shfl(cum, e));   // incl[e] = end of expert e's run
    if (re > rb) {
      const u16*   wEL = wpk + ((size_t)e << 16) + (lane << 3);
      const float* wF  = w32 + ((size_t)e << 16);

      f32x4 acc[2][4];
      const f32x4 zero = {0.f, 0.f, 0.f, 0.f};
#pragma unroll
      for (int m = 0; m < 2; ++m)
#pragma unroll
        for (int n = 0; n < 4; ++n) acc[m][n] = zero;

      BF8 bA[2][4], bB[2][4];

      if (first) {
        // prologue: B0[8] S0[2] S1[2] -> 12 outstanding
        loadBstep<WSBF>(wEL, wF, wv, l15, lg, 0, bA);
#pragma unroll
        for (int i = 0; i < 2; ++i) GLDS(gp[i] +   0, lbase +     0 + i * 1024);
#pragma unroll
        for (int i = 0; i < 2; ++i) GLDS(gp[i] +  64, lbase +  8192 + i * 1024);

        // I0: +B1[8]+S2[2]=22; VMW(12) retires B0,S0; compute buf0
        loadBstep<WSBF>(wEL, wF, wv, l15, lg, 1, bB);
#pragma unroll
        for (int i = 0; i < 2; ++i) GLDS(gp[i] + 128, lbase + 16384 + i * 1024);
        VMW("12"); BAR();
        computeStep(sAc, 0, l15, lg, bA, acc);

        // I1: +B2[8]+S3[2]=22; VMW(12) retires S1,B1; compute buf1
        loadBstep<WSBF>(wEL, wF, wv, l15, lg, 2, bA);
#pragma unroll
        for (int i = 0; i < 2; ++i) GLDS(gp[i] + 192, lbase + 24576 + i * 1024);
        VMW("12"); BAR();
        computeStep(sAc, 1, l15, lg, bB, acc);

        // I2: +B3[8]=20; VMW(10) retires S2,B2; compute buf2
        loadBstep<WSBF>(wEL, wF, wv, l15, lg, 3, bB);
        VMW("10"); BAR();
        computeStep(sAc, 2, l15, lg, bA, acc);

        // I3: VMW(0) retires S3,B3; compute buf3
        VMW("0"); BAR();
        computeStep(sAc, 3, l15, lg, bB, acc);
        first = false;
      } else {
        // boundary-tile re-run: A already staged (identical data); B-only
        loadBstep<WSBF>(wEL, wF, wv, l15, lg, 0, bA);
        loadBstep<WSBF>(wEL, wF, wv, l15, lg, 1, bB);
        computeStep(sAc, 0, l15, lg, bA, acc);
        loadBstep<WSBF>(wEL, wF, wv, l15, lg, 2, bA);
        computeStep(sAc, 1, l15, lg, bB, acc);
        loadBstep<WSBF>(wEL, wF, wv, l15, lg, 3, bB);
        computeStep(sAc, 2, l15, lg, bA, acc);
        computeStep(sAc, 3, l15, lg, bB, acc);
      }

      // ---- epilogue (C/D map: col=l15, row=lg*4+j) ----
      const bool full = (rb == t0) & (re == t1);
      if (full) {
#pragma unroll
        for (int m = 0; m < 2; ++m) {
          const int rbase = t0 + (m << 4) + (lg << 2);
#pragma unroll
          for (int n = 0; n < 4; ++n) {
            float* op = out + (size_t)rbase * NOUT + (wv << 6) + (n << 4) + l15;
#pragma unroll
            for (int j = 0; j < 4; ++j) op[(size_t)j * NOUT] = acc[m][n][j];
          }
        }
      } else {
#pragma unroll
        for (int m = 0; m < 2; ++m) {
          const int rbase = t0 + (m << 4) + (lg << 2);
#pragma unroll
          for (int n = 0; n < 4; ++n) {
            float* op = out + (size_t)rbase * NOUT + (wv << 6) + (n << 4) + l15;
#pragma unroll
            for (int j = 0; j < 4; ++j) {
              const int rg = rbase + j;
              if (rg >= rb && rg < re) op[(size_t)j * NOUT] = acc[m][n][j];
            }
          }
        }
      }
    }
    rb = re > rb ? re : rb;
    ++e;
  }
}

extern "C" void kernel_launch(void* const* d_in, const int* in_sizes, int n_in,
                              void* d_out, int out_size, void* d_ws, size_t ws_size,
                              hipStream_t stream) {
  const float* inp    = (const float*)d_in[0];
  const float* w      = (const float*)d_in[1];
  const int*   counts = (const int*)d_in[2];
  float*       out    = (float*)d_out;

  const size_t wbytes = (size_t)NEXPERT * NOUT * KIN * 2;  // 4 MB packed bf16 W
  const bool usews = (ws_size >= wbytes);

  if (usews) {
    u16* wpk = (u16*)d_ws;
    pack_w_kernel<<<1024, 256, 0, stream>>>(w, wpk);
    moe_gemm_kernel<true><<<NTOK / BM, 256, 0, stream>>>(inp, w, wpk, counts, out);
  } else {
    moe_gemm_kernel<false><<<NTOK / BM, 256, 0, stream>>>(inp, w, nullptr, counts, out);
  }
}

// Round 11
// 312.564 us; speedup vs baseline: 1.0779x; 1.0779x over previous
//
#include <hip/hip_runtime.h>
#include <cstdint>
#include <cstddef>

#define NEXPERT 32
#define KIN 256
#define NOUT 256
#define NTOK 524288

typedef float f32x4 __attribute__((ext_vector_type(4)));
typedef __bf16 bf16x8 __attribute__((ext_vector_type(8)));
typedef unsigned short u16;
typedef u16 u16x8 __attribute__((ext_vector_type(8)));
typedef unsigned int u32;

union BF8 { u16x8 u; bf16x8 b; };

__device__ __forceinline__ u16 f2bf(float f) {
  unsigned u = __float_as_uint(f);
  return (u16)((u + 0x7FFFu + ((u >> 16) & 1u)) >> 16);  // RNE
}

__device__ __forceinline__ void cvt8(const float4& x, const float4& y, BF8& o) {
  o.u[0]=f2bf(x.x); o.u[1]=f2bf(x.y); o.u[2]=f2bf(x.z); o.u[3]=f2bf(x.w);
  o.u[4]=f2bf(y.x); o.u[5]=f2bf(y.y); o.u[6]=f2bf(y.z); o.u[7]=f2bf(y.w);
}

#define GLDS(gp, lp) __builtin_amdgcn_global_load_lds(                      \
    (const __attribute__((address_space(1))) u32*)(gp),                      \
    (__attribute__((address_space(3))) u32*)(u32)(uintptr_t)(lp), 16, 0, 0)

#define VMW(n) asm volatile("s_waitcnt vmcnt(" n ")" ::: "memory")

// ---- prologue: pack W fp32 -> bf16 in MFMA-fragment order ----
// 16B unit t = ((e*8 + kc)*16 + n16)*64 + lane;
// lane holds W[e][n16*16 + (lane&15)][kc*32 + (lane>>4)*8 + j], j=0..7.
__global__ void pack_w_kernel(const float* __restrict__ w, u16* __restrict__ wb) {
  const int t    = blockIdx.x * 256 + threadIdx.x;   // 0..262143
  const int lane = t & 63;
  const int n16  = (t >> 6) & 15;
  const int kc   = (t >> 10) & 7;
  const int e    = t >> 13;
  const float* src = w + (size_t)e * 65536 + (size_t)(n16 * 16 + (lane & 15)) * 256
                       + kc * 32 + (lane >> 4) * 8;
  const float4 a = *reinterpret_cast<const float4*>(src);
  const float4 b = *reinterpret_cast<const float4*>(src + 4);
  u16x8 h;
  h[0]=f2bf(a.x); h[1]=f2bf(a.y); h[2]=f2bf(a.z); h[3]=f2bf(a.w);
  h[4]=f2bf(b.x); h[5]=f2bf(b.y); h[6]=f2bf(b.z); h[7]=f2bf(b.w);
  *reinterpret_cast<u16x8*>(wb + (size_t)t * 8) = h;
}

// ---- 8 B-fragments (one quarter: k-chunk kc, n16 = nb..nb+7) ----
template<bool WSBF>
__device__ __forceinline__ void loadBq(const u16* wEL, const float* wF,
                                       int l15, int lg, int kc, int nb, BF8 (&d)[8]) {
  if (WSBF) {
#pragma unroll
    for (int j = 0; j < 8; ++j)
      d[j].u = *reinterpret_cast<const u16x8*>(wEL + (size_t)(kc * 16 + nb + j) * 512);
  } else {
#pragma unroll
    for (int j = 0; j < 8; ++j) {
      const float4* p = reinterpret_cast<const float4*>(
          wF + (size_t)((nb + j) * 16 + l15) * KIN + kc * 32 + lg * 8);
      cvt8(p[0], p[1], d[j]);
    }
  }
}

// ---- A fragment for k-half c of one staged step (swizzled private LDS) ----
__device__ __forceinline__ void loadAf(const char* abase, int c, int l15, int lg, BF8& af) {
  const int g0 = (c << 3) + (lg << 1);
  const f32x4 fa = *reinterpret_cast<const f32x4*>(abase + (((g0    ) ^ l15) << 4));
  const f32x4 fb = *reinterpret_cast<const f32x4*>(abase + (((g0 + 1) ^ l15) << 4));
  af.b[0]=(__bf16)fa[0]; af.b[1]=(__bf16)fa[1];
  af.b[2]=(__bf16)fa[2]; af.b[3]=(__bf16)fa[3];
  af.b[4]=(__bf16)fb[0]; af.b[5]=(__bf16)fb[1];
  af.b[6]=(__bf16)fb[2]; af.b[7]=(__bf16)fb[3];
}

#define MFMA8(AF, BQ, NB)                                                    \
  _Pragma("unroll") for (int j_ = 0; j_ < 8; ++j_)                           \
    acc[(NB) + j_] = __builtin_amdgcn_mfma_f32_16x16x32_bf16(                \
        (AF).b, (BQ)[j_].b, acc[(NB) + j_], 0, 0, 0);

// ---- BARRIER-FREE grouped GEMM: wave-private 16x256 tiles ----
// block = 4 waves; wave w owns tokens [blk*64 + w*16, +16), ALL 256 cols.
// A: 16 KB private LDS per wave (4 bufs x 4KB), GLDS pre-swizzled source.
// B: per-K-step quarter loads (8 frags), ping-pong b0/b1, counted vmcnt.
// No s_barrier anywhere: every wave is an independent pipeline.
template<bool WSBF>
__global__ __launch_bounds__(256)
void moe_gemm_kernel(const float* __restrict__ inp,
                     const float* w32,
                     const u16* __restrict__ wpk,
                     const int* __restrict__ counts,
                     float* __restrict__ out)
{
  __shared__ float sA[16384];   // 64 KB = 4 waves x 16 KB private

  const int tid  = threadIdx.x;
  const int lane = tid & 63;
  const int wv   = tid >> 6;
  const int l15  = lane & 15;
  const int lg   = lane >> 4;

  // per-wave INCLUSIVE cumsum of counts via shuffle scan (int32/int64 probe)
  const long long* c64 = reinterpret_cast<const long long*>(counts);
  const long long p0 = c64[0];
  const bool is64 = (p0 >= 0 && p0 < (1ll << 31));
  int c = 0;
  if (lane < 32) c = is64 ? (int)c64[lane] : counts[lane];
#pragma unroll
  for (int d = 1; d < 32; d <<= 1) {
    const int o = __shfl_up(c, d, 64);
    if (lane >= d) c += o;
  }
  const int cum = (lane < 32) ? c : 0x7fffffff;

  const int t0w = blockIdx.x * 64 + (wv << 4);   // wave's 16 tokens
  const int t1w = t0w + 16;

  // stage pointers: instr i covers own rows i*4+(lane>>4);
  // physical 16B unit u'=lane&15 <- logical g = u' ^ (row&15)
  const float* gp[4];
#pragma unroll
  for (int i = 0; i < 4; ++i) {
    const int r = (i << 2) + (lane >> 4);          // 0..15 within wave tile
    const int g = (lane & 15) ^ r;
    gp[i] = inp + (size_t)(t0w + r) * KIN + g * 4;
  }
  char* const lbase = reinterpret_cast<char*>(sA) + wv * 16384;  // + s*4096 + i*1024
  const char* const rbase0 = lbase + l15 * 256;                  // + s*4096 read base

  int rb = t0w;
  int e  = __popcll(__ballot(cum <= t0w));
  bool first = true;

  while (rb < t1w) {
    const int re = min(t1w, __shfl(cum, e));   // incl[e] = end of expert e's run
    if (re > rb) {
      const u16*   wEL = wpk + ((size_t)e << 16) + (lane << 3);
      const float* wF  = w32 + ((size_t)e << 16);

      f32x4 acc[16];
      const f32x4 zero = {0.f, 0.f, 0.f, 0.f};
#pragma unroll
      for (int n = 0; n < 16; ++n) acc[n] = zero;

      BF8 b0[8], b1[8], af0, af1;

      if (first) {
        // prologue queue: S0(4) b0(8) S1(4) S2(4)
#pragma unroll
        for (int i = 0; i < 4; ++i) GLDS(gp[i] +   0, lbase +     0 + i * 1024);
        loadBq<WSBF>(wEL, wF, l15, lg, 0, 0, b0);
#pragma unroll
        for (int i = 0; i < 4; ++i) GLDS(gp[i] +  64, lbase +  4096 + i * 1024);
#pragma unroll
        for (int i = 0; i < 4; ++i) GLDS(gp[i] + 128, lbase +  8192 + i * 1024);

        // ---- s=0 ----
        loadBq<WSBF>(wEL, wF, l15, lg, 0, 8, b1);  VMW("16");
        loadAf(rbase0 +     0, 0, l15, lg, af0);   MFMA8(af0, b0, 0);
        loadBq<WSBF>(wEL, wF, l15, lg, 1, 0, b0);  VMW("8");
        MFMA8(af0, b1, 8);
        loadBq<WSBF>(wEL, wF, l15, lg, 1, 8, b1);  VMW("8");
        loadAf(rbase0 +     0, 1, l15, lg, af1);   MFMA8(af1, b0, 0);
        loadBq<WSBF>(wEL, wF, l15, lg, 2, 0, b0);
#pragma unroll
        for (int i = 0; i < 4; ++i) GLDS(gp[i] + 192, lbase + 12288 + i * 1024);
        VMW("12");                                  MFMA8(af1, b1, 8);
        // ---- s=1 ----
        loadBq<WSBF>(wEL, wF, l15, lg, 2, 8, b1);  VMW("12");
        loadAf(rbase0 +  4096, 0, l15, lg, af0);   MFMA8(af0, b0, 0);
        loadBq<WSBF>(wEL, wF, l15, lg, 3, 0, b0);  VMW("8");
        MFMA8(af0, b1, 8);
        loadBq<WSBF>(wEL, wF, l15, lg, 3, 8, b1);  VMW("8");
        loadAf(rbase0 +  4096, 1, l15, lg, af1);   MFMA8(af1, b0, 0);
        loadBq<WSBF>(wEL, wF, l15, lg, 4, 0, b0);  VMW("8");
        MFMA8(af1, b1, 8);
        // ---- s=2 ----
        loadBq<WSBF>(wEL, wF, l15, lg, 4, 8, b1);  VMW("8");
        loadAf(rbase0 +  8192, 0, l15, lg, af0);   MFMA8(af0, b0, 0);
        loadBq<WSBF>(wEL, wF, l15, lg, 5, 0, b0);  VMW("8");
        MFMA8(af0, b1, 8);
        loadBq<WSBF>(wEL, wF, l15, lg, 5, 8, b1);  VMW("8");
        loadAf(rbase0 +  8192, 1, l15, lg, af1);   MFMA8(af1, b0, 0);
        loadBq<WSBF>(wEL, wF, l15, lg, 6, 0, b0);  VMW("8");
        MFMA8(af1, b1, 8);
        // ---- s=3 ----
        loadBq<WSBF>(wEL, wF, l15, lg, 6, 8, b1);  VMW("8");
        loadAf(rbase0 + 12288, 0, l15, lg, af0);   MFMA8(af0, b0, 0);
        loadBq<WSBF>(wEL, wF, l15, lg, 7, 0, b0);  VMW("8");
        MFMA8(af0, b1, 8);
        loadBq<WSBF>(wEL, wF, l15, lg, 7, 8, b1);  VMW("8");
        loadAf(rbase0 + 12288, 1, l15, lg, af1);   MFMA8(af1, b0, 0);
        VMW("0");                                   MFMA8(af1, b1, 8);
        first = false;
      } else {
        // boundary re-run (rare): A already staged; serial B quarters
#pragma unroll
        for (int s = 0; s < 4; ++s) {
          loadBq<WSBF>(wEL, wF, l15, lg, 2 * s, 0, b0);
          loadBq<WSBF>(wEL, wF, l15, lg, 2 * s, 8, b1);
          VMW("0");
          loadAf(rbase0 + s * 4096, 0, l15, lg, af0);
          MFMA8(af0, b0, 0); MFMA8(af0, b1, 8);
          loadBq<WSBF>(wEL, wF, l15, lg, 2 * s + 1, 0, b0);
          loadBq<WSBF>(wEL, wF, l15, lg, 2 * s + 1, 8, b1);
          VMW("0");
          loadAf(rbase0 + s * 4096, 1, l15, lg, af1);
          MFMA8(af1, b0, 0); MFMA8(af1, b1, 8);
        }
      }

      // ---- store (C/D map: col=l15 -> out col n*16+l15; row=lg*4+j) ----
      const bool full = (rb == t0w) & (re == t1w);
      if (full) {
#pragma unroll
        for (int n = 0; n < 16; ++n) {
          float* op = out + (size_t)(t0w + (lg << 2)) * NOUT + n * 16 + l15;
#pragma unroll
          for (int j = 0; j < 4; ++j) op[(size_t)j * NOUT] = acc[n][j];
        }
      } else {
#pragma unroll
        for (int n = 0; n < 16; ++n) {
          float* op = out + (size_t)(t0w + (lg << 2)) * NOUT + n * 16 + l15;
#pragma unroll
          for (int j = 0; j < 4; ++j) {
            const int rg = t0w + (lg << 2) + j;
            if (rg >= rb && rg < re) op[(size_t)j * NOUT] = acc[n][j];
          }
        }
      }
    }
    rb = re > rb ? re : rb;
    ++e;
  }
}

extern "C" void kernel_launch(void* const* d_in, const int* in_sizes, int n_in,
                              void* d_out, int out_size, void* d_ws, size_t ws_size,
                              hipStream_t stream) {
  const float* inp    = (const float*)d_in[0];
  const float* w      = (const float*)d_in[1];
  const int*   counts = (const int*)d_in[2];
  float*       out    = (float*)d_out;

  const size_t wbytes = (size_t)NEXPERT * NOUT * KIN * 2;  // 4 MB packed bf16 W
  const bool usews = (ws_size >= wbytes);

  if (usews) {
    u16* wpk = (u16*)d_ws;
    pack_w_kernel<<<1024, 256, 0, stream>>>(w, wpk);
    moe_gemm_kernel<true><<<NTOK / 64, 256, 0, stream>>>(inp, w, wpk, counts, out);
  } else {
    moe_gemm_kernel<false><<<NTOK / 64, 256, 0, stream>>>(inp, w, nullptr, counts, out);
  }
}